// Round 2
// baseline (186.162 us; speedup 1.0000x reference)
//
#include <hip/hip_runtime.h>

// KAN cubic-spline elementwise: out = id_gain[c]*x + spline(clamp(a[c]*x+b[c])) + bias[c]
// B=32, C=192, H=64, W=64, K=32.  Total elems = 25,165,824 (fp32).
// Memory-bound: ~201 MB traffic -> ~32 us floor at 6.3 TB/s.

#define TOTAL_ELEMS 25165824
#define TOTAL4      6291456   // float4 count
#define PLANE4      1024      // H*W/4 float4 per channel plane
#define NCH         192
#define BLOCKS      2048
#define TPB         256

__device__ __forceinline__ float kan_elem(float xx, float a_c, float b_c,
                                          float g_c, float s_c, float av) {
    float xa = fmaf(xx, a_c, b_c);
    xa = fminf(fmaxf(xa, -1.5f), 1.5f);
    float u  = (xa + 1.0f) * 15.5f;      // 0.5*(K-1) = 15.5
    float fi = floorf(u);
    int   i  = (int)fi;
    float t  = u - fi;                   // in [0,1)
    int i0 = min(max(i - 1, 0), 31);
    int i1 = min(max(i,     0), 31);
    int i2 = min(max(i + 1, 0), 31);
    int i3 = min(max(i + 2, 0), 31);
    // alpha row lives in lanes 0..31 (dup in 32..63); data-dependent taps via
    // ds_bpermute (conflict-free crossbar), not LDS gather.
    float a0 = __shfl(av, i0, 64);
    float a1 = __shfl(av, i1, 64);
    float a2 = __shfl(av, i2, 64);
    float a3 = __shfl(av, i3, 64);
    float t2 = t * t, t3 = t2 * t;
    const float k6 = 1.0f / 6.0f;
    float w0 = (1.0f - 3.0f*t + 3.0f*t2 -      t3) * k6;
    float w1 = (4.0f -           6.0f*t2 + 3.0f*t3) * k6;
    float w2 = (1.0f + 3.0f*t + 3.0f*t2 - 3.0f*t3) * k6;
    float w3 = t3 * k6;
    float spline = a0*w0 + a1*w1 + a2*w2 + a3*w3;
    return fmaf(g_c, xx, spline + s_c);
}

__global__ __launch_bounds__(TPB) void kan_cubic_kernel(
    const float* __restrict__ x, const float* __restrict__ a,
    const float* __restrict__ b, const float* __restrict__ alpha,
    const float* __restrict__ id_gain, const float* __restrict__ bias,
    float* __restrict__ out)
{
    const int j = threadIdx.x & 31;  // alpha column held by this lane
    int g = blockIdx.x * TPB + threadIdx.x;
    // TOTAL4 == BLOCKS*TPB*12 exactly -> no tail, all lanes always active.
    #pragma unroll 1
    for (; g < TOTAL4; g += BLOCKS * TPB) {
        // 64 consecutive float4s never straddle a 1024-float4 plane boundary
        // -> channel is wave-uniform; assert via readfirstlane for scalar loads.
        int c = (g >> 10) % NCH;
        c = __builtin_amdgcn_readfirstlane(c);
        float a_c = a[c];
        float b_c = b[c];
        float g_c = id_gain[c];
        float s_c = bias[c];
        float av  = alpha[(c << 5) + j];   // wave holds the full 32-entry row

        float4 xv = reinterpret_cast<const float4*>(x)[g];
        float4 ov;
        ov.x = kan_elem(xv.x, a_c, b_c, g_c, s_c, av);
        ov.y = kan_elem(xv.y, a_c, b_c, g_c, s_c, av);
        ov.z = kan_elem(xv.z, a_c, b_c, g_c, s_c, av);
        ov.w = kan_elem(xv.w, a_c, b_c, g_c, s_c, av);
        reinterpret_cast<float4*>(out)[g] = ov;
    }
}

extern "C" void kernel_launch(void* const* d_in, const int* in_sizes, int n_in,
                              void* d_out, int out_size, void* d_ws, size_t ws_size,
                              hipStream_t stream) {
    const float* x       = (const float*)d_in[0];
    const float* a       = (const float*)d_in[1];
    const float* b       = (const float*)d_in[2];
    const float* alpha   = (const float*)d_in[3];
    const float* id_gain = (const float*)d_in[4];
    const float* bias    = (const float*)d_in[5];
    float* out = (float*)d_out;
    kan_cubic_kernel<<<BLOCKS, TPB, 0, stream>>>(x, a, b, alpha, id_gain, bias, out);
}